// Round 10
// baseline (455.731 us; speedup 1.0000x reference)
//
#include <hip/hip_runtime.h>
#include <hip/hip_bf16.h>

typedef __attribute__((ext_vector_type(4))) float f32x4;
typedef __attribute__((ext_vector_type(8))) short short8;

__device__ __forceinline__ float bf2f(ushort u) {
    union { unsigned int u; float f; } x; x.u = ((unsigned int)u) << 16; return x.f;
}
__device__ __forceinline__ ushort f2bf(float f) {
    union { float f; unsigned int u; } x; x.f = f;
    unsigned int u = x.u;
    unsigned int r = (u + 0x7fffu + ((u >> 16) & 1u)) >> 16;  // RNE
    return (ushort)r;
}
__device__ __forceinline__ void gload16(const ushort* g, ushort* l) {
    __builtin_amdgcn_global_load_lds(
        (const __attribute__((address_space(1))) unsigned int*)g,
        (__attribute__((address_space(3))) unsigned int*)l, 16, 0, 0);
}

// ---------------------------------------------------------------------------
// k_front: grid 2048.  EVERY block b: l_emb for sample b -> c0 (bf16).
// Blocks 0..255 additionally repack Wa[a][o][t*256+i] = bf16(m[a][t]*W[o,i,t]).
// Block 256 additionally zeroes cnt/loss/acc and buckets samples by action.
// ---------------------------------------------------------------------------
__global__ __launch_bounds__(256) void k_front(
    const float* __restrict__ conv_w, const float* __restrict__ a_table,
    const float* __restrict__ a_W, const float* __restrict__ a_b,
    const int* __restrict__ actions, const float* __restrict__ mapt,
    const int* __restrict__ lms, int* __restrict__ cnt,
    int* __restrict__ list, ushort* __restrict__ Wa,
    ushort* __restrict__ c0, float* __restrict__ out_head)
{
    const int bid = blockIdx.x, tid = threadIdx.x;

    // ---- l_emb for sample bid (all blocks) ----
    {
        const int e4 = (tid & 63) * 4, pw = tid >> 6;
        #pragma unroll
        for (int pp = 0; pp < 4; ++pp) {
            const int p = pw * 4 + pp;
            const int* lm = lms + (bid * 16 + p) * 8;
            float4 s = make_float4(0.f, 0.f, 0.f, 0.f);
            #pragma unroll
            for (int k = 0; k < 8; ++k) {
                const int idx = lm[k];
                if (idx) {
                    const float4 v = *(const float4*)&mapt[idx * 256 + e4];
                    s.x += v.x; s.y += v.y; s.z += v.z; s.w += v.w;
                }
            }
            ushort o4[4] = { f2bf(s.x), f2bf(s.y), f2bf(s.z), f2bf(s.w) };
            *(uint2*)&c0[(size_t)(bid * 16 + p) * 256 + e4] = *(const uint2*)o4;
        }
    }

    if (bid < 256) {
        __shared__ float ao[4][9];
        __shared__ float m[4][9];
        if (tid < 36) {
            const int a = tid / 9, t = tid % 9;
            float s = a_b[t];
            for (int c = 0; c < 32; c++) s += a_table[a * 32 + c] * a_W[t * 32 + c];
            ao[a][t] = s;
        }
        __syncthreads();
        if (tid < 4) {
            float mx = -1e30f;
            for (int t = 0; t < 9; t++) mx = fmaxf(mx, ao[tid][t]);
            float e[9], z = 0.f;
            for (int t = 0; t < 9; t++) { e[t] = expf(ao[tid][t] - mx); z += e[t]; }
            for (int t = 0; t < 9; t++) m[tid][t] = e[t] / z;
        }
        __syncthreads();
        const int o = bid;
        float w9[9];
        #pragma unroll
        for (int t = 0; t < 9; t++) w9[t] = conv_w[(o * 256 + tid) * 9 + t];
        #pragma unroll
        for (int a = 0; a < 4; a++)
            #pragma unroll
            for (int t = 0; t < 9; t++)
                Wa[(size_t)((a << 8) + o) * 2304 + t * 256 + tid] = f2bf(m[a][t] * w9[t]);
    } else if (bid == 256) {
        if (tid < 12) cnt[tid] = 0;
        if (tid == 0) { out_head[0] = 0.f; out_head[1] = 0.f; }
        __syncthreads();
        for (int it = 0; it < 24; it++) {
            const int idx = it * 256 + tid;          // 0..6143
            const int jj = idx >> 11, b = idx & 2047;
            const int av = actions[b * 3 + jj];
            const int pos = atomicAdd(&cnt[jj * 4 + av], 1);
            list[((jj * 4 + av) << 11) + pos] = b;
        }
    }
}

// ---------------------------------------------------------------------------
// k_conv v6: counted-vmcnt 3-buffer A-pipeline (T3+T4) + B-in-LDS.
// BM=128 (om half), BN=128 (8 same-action samples), BK=64, 512 threads
// (8 waves: 2M x 4N), wave tile 64x32 -> 16 MFMA + 12 ds_read_b128 per wave
// per K-step; per CU 128 MFMA/step (~516 cyc) vs ~145 cyc LDS -> MFMA-bound.
// A staged via global_load_lds into 3 rotating 16 KB buffers; each iteration:
// s_waitcnt vmcnt(2) (one stage stays in flight) + raw s_barrier.  B staged
// once (64 KB, XOR-swizzled); zero-padding via per-lane cndmask.
// LDS 112 KB -> 1 block/CU.  Grid 2048 = 8 slots (a,om) x 256 groups;
// slot = bid&7 for XCD L2 affinity of the 0.59 MB Wa half.
// ---------------------------------------------------------------------------
__global__ __launch_bounds__(512, 1) void k_conv(
    const ushort* __restrict__ cur, const ushort* __restrict__ Wa,
    const int* __restrict__ cnt, const int* __restrict__ list,
    const int j, ushort* __restrict__ outp)
{
    __shared__ __align__(16) ushort Alds[3][128 * 64];   // 3 x 16 KB
    __shared__ __align__(16) ushort Blds[8 * 16 * 256];  // 64 KB
    const int tid = threadIdx.x, bid = blockIdx.x;
    const int a = bid & 3, om = (bid >> 2) & 1, grp = bid >> 3;
    const int ca = cnt[j * 4 + a];
    if (grp * 8 >= ca) return;            // uniform exit before any barrier
    const int* la = list + ((j * 4 + a) << 11) + grp * 8;

    const int wid = tid >> 6, lane = tid & 63;
    const int l15 = lane & 15, l4 = lane >> 4;
    const int wm = wid >> 2, wn = wid & 3;

    // ---- stage B once: wave wid -> sample slot wid; XOR-swizzled chunks ----
    {
        const int sw = (grp * 8 + wid < ca) ? la[wid] : la[0];
        const ushort* src = cur + (size_t)sw * 4096;
        const int p = lane >> 2, cg = lane & 3;
        ushort* dst = Blds + wid * 4096 + p * 256;
        const ushort* s2 = src + p * 256;
        #pragma unroll
        for (int qq = 0; qq < 8; ++qq) {
            const int c = qq * 4 + cg;
            const uint4 v = *(const uint4*)(s2 + c * 8);
            *(uint4*)(dst + ((c ^ (p & 7)) * 8)) = v;
        }
    }

    int sid[2]; bool vst[2];
    #pragma unroll
    for (int nf = 0; nf < 2; ++nf) {
        const int sl = wn * 2 + nf;
        vst[nf] = (grp * 8 + sl) < ca;
        sid[nf] = vst[nf] ? la[sl] : 0;
    }

    // ---- A staging: 2 x gload16/thread per stage fills 128x64 (16 KB) ----
    // unit u = qq*512+tid: row=u>>3, c=u&7; src chunk = c ^ (row&7).
    const ushort* wbase = Wa + (size_t)((a << 8) + om * 128) * 2304;
    #define STAGE(buf, k0)                                                     \
        _Pragma("unroll")                                                      \
        for (int qq = 0; qq < 2; ++qq) {                                       \
            const int u = qq * 512 + tid;                                      \
            const int row = u >> 3;                                            \
            const int cc = (u & 7) ^ (row & 7);                                \
            gload16(wbase + (size_t)row * 2304 + (k0) + cc * 8,                \
                    &Alds[buf][u * 8]);                                        \
        }

    f32x4 acc[4][2];
    #pragma unroll
    for (int mf = 0; mf < 4; ++mf) {
        acc[mf][0] = (f32x4){0.f, 0.f, 0.f, 0.f};
        acc[mf][1] = (f32x4){0.f, 0.f, 0.f, 0.f};
    }

    const int ph = l15 >> 2, pw = l15 & 3;
    const short8 bzero = {0, 0, 0, 0, 0, 0, 0, 0};
    const ushort* bbase0 = Blds + (wn * 2 + 0) * 4096;
    const ushort* bbase1 = Blds + (wn * 2 + 1) * 4096;
    const int asw = l15 & 7;             // A-row swizzle key (rr&7 == l15&7)

    // compute body for K-step ks reading A buffer rd
    #define COMPUTE(ks, rd)                                                    \
        {                                                                      \
            const int t = (ks) >> 2;                                           \
            const int td = (t * 11) >> 5, tm = t - td * 3;                     \
            const int hh = ph + td - 1, ww = pw + tm - 1;                      \
            const bool xv = (hh >= 0) & (hh < 4) & (ww >= 0) & (ww < 4);       \
            const int brow = xv ? ((hh << 2) + ww) : 0;                        \
            const int rb = brow * 256, rx = brow & 7;                          \
            _Pragma("unroll")                                                  \
            for (int kf = 0; kf < 2; ++kf) {                                   \
                const int bch = ((((ks) & 3) * 8 + kf * 4 + l4) ^ rx) * 8;     \
                short8 b0 = *(const short8*)(bbase0 + rb + bch);               \
                short8 b1 = *(const short8*)(bbase1 + rb + bch);               \
                if (!xv) { b0 = bzero; b1 = bzero; }                           \
                const int acx = ((kf * 4 + l4) ^ asw) * 8;                     \
                _Pragma("unroll")                                              \
                for (int mf = 0; mf < 4; ++mf) {                               \
                    const int rr = wm * 64 + mf * 16 + l15;                    \
                    const short8 af =                                          \
                        *(const short8*)&Alds[rd][rr * 64 + acx];              \
                    acc[mf][0] = __builtin_amdgcn_mfma_f32_16x16x32_bf16(      \
                        af, b0, acc[mf][0], 0, 0, 0);                          \
                    acc[mf][1] = __builtin_amdgcn_mfma_f32_16x16x32_bf16(      \
                        af, b1, acc[mf][1], 0, 0, 0);                          \
                }                                                              \
            }                                                                  \
        }

    STAGE(0, 0);
    STAGE(1, 64);
    asm volatile("s_waitcnt lgkmcnt(0)" ::: "memory");   // B ds_writes done

    int rd = 0, st = 2;                  // rd = ks%3, st = (ks+2)%3
    for (int ks = 0; ks < 34; ++ks) {
        asm volatile("s_waitcnt vmcnt(2)" ::: "memory"); // stage ks landed
        __builtin_amdgcn_s_barrier();                    // visible to all
        __builtin_amdgcn_sched_barrier(0);
        STAGE(st, (ks + 2) * 64);                        // stays in flight
        COMPUTE(ks, rd);
        rd = (rd == 2) ? 0 : rd + 1;
        st = (st == 2) ? 0 : st + 1;
    }
    asm volatile("s_waitcnt vmcnt(2)" ::: "memory");
    __builtin_amdgcn_s_barrier();
    __builtin_amdgcn_sched_barrier(0);
    COMPUTE(34, rd);
    rd = (rd == 2) ? 0 : rd + 1;
    asm volatile("s_waitcnt vmcnt(0)" ::: "memory");
    __builtin_amdgcn_s_barrier();
    __builtin_amdgcn_sched_barrier(0);
    COMPUTE(35, rd);

    // epilogue: C frag col=l15 (=p), row=l4*4+r (=o within 16-tile)
    #pragma unroll
    for (int nf = 0; nf < 2; ++nf) {
        if (!vst[nf]) continue;                      // wave-uniform branch
        const size_t rowb = ((size_t)sid[nf] * 16 + l15) * 256;
        #pragma unroll
        for (int mf = 0; mf < 4; ++mf) {
            const int ob = om * 128 + wm * 64 + mf * 16 + l4 * 4;
            ushort o4[4];
            #pragma unroll
            for (int r = 0; r < 4; r++) o4[r] = f2bf(acc[mf][nf][r]);
            *(uint2*)&outp[rowb + ob] = *(const uint2*)o4;
        }
    }
    #undef STAGE
    #undef COMPUTE
}

// ---------------------------------------------------------------------------
// k_final: grid B=2048.  emb in-block (17-padded LDS), vectorized bf16 dot,
// shfl_xor 16-lane reduction, softmax chain, loss/acc atomics.
// ---------------------------------------------------------------------------
__global__ __launch_bounds__(256) void k_final(
    const ushort* __restrict__ c0, const ushort* __restrict__ c1,
    const ushort* __restrict__ c2, const ushort* __restrict__ c3,
    const float* __restrict__ gold, const int* __restrict__ gs,
    const int* __restrict__ y, float* __restrict__ d_out)
{
    __shared__ float embl[4][272];
    __shared__ float lg[16];
    const int b = blockIdx.x, tid = threadIdx.x;
    {
        const int s = tid >> 6, e0 = (tid & 63) * 4;
        const int* g = gs + b * 64 + s * 16;
        float4 accv = make_float4(0.f, 0.f, 0.f, 0.f);
        #pragma unroll
        for (int l = 0; l < 16; l++) {
            const float4 v = *(const float4*)&gold[g[l] * 256 + e0];
            accv.x += v.x; accv.y += v.y; accv.z += v.z; accv.w += v.w;
        }
        float* dst = &embl[s][(e0 >> 4) * 17 + (e0 & 15)];
        dst[0] = accv.x; dst[1] = accv.y; dst[2] = accv.z; dst[3] = accv.w;
    }
    __syncthreads();
    const int p = tid >> 4, g16 = tid & 15;
    const ushort* rows[4] = {
        c0 + (size_t)(b * 16 + p) * 256, c1 + (size_t)(b * 16 + p) * 256,
        c2 + (size_t)(b * 16 + p) * 256, c3 + (size_t)(b * 16 + p) * 256 };
    float acc = 0.f;
    #pragma unroll
    for (int s = 0; s < 4; s++) {
        const ushort* row = rows[s] + g16 * 16;
        const uint4 v0 = *(const uint4*)row;
        const uint4 v1 = *(const uint4*)(row + 8);
        const ushort* pv0 = (const ushort*)&v0;
        const ushort* pv1 = (const ushort*)&v1;
        const float* eb = &embl[s][g16 * 17];
        #pragma unroll
        for (int q = 0; q < 8; q++) acc += bf2f(pv0[q]) * eb[q];
        #pragma unroll
        for (int q = 0; q < 8; q++) acc += bf2f(pv1[q]) * eb[8 + q];
    }
    acc += __shfl_xor(acc, 1);
    acc += __shfl_xor(acc, 2);
    acc += __shfl_xor(acc, 4);
    acc += __shfl_xor(acc, 8);
    if (g16 == 0) lg[p] = acc;
    __syncthreads();
    if (tid == 0) {
        float mx = -1e30f;
        for (int q = 0; q < 16; q++) mx = fmaxf(mx, lg[q]);
        float ex[16], z = 0.f;
        for (int q = 0; q < 16; q++) { ex[q] = expf(lg[q] - mx); z += ex[q]; }
        float prob[16];
        for (int q = 0; q < 16; q++) {
            prob[q] = ex[q] / z;
            d_out[2 + b * 16 + q] = prob[q];
        }
        int am = 0; float bv = prob[0];
        for (int q = 1; q < 16; q++) if (prob[q] > bv) { bv = prob[q]; am = q; }
        const int yt = y[b * 2] * 4 + y[b * 2 + 1];
        float z2 = 0.f;
        for (int q = 0; q < 16; q++) z2 += expf(prob[q]);
        const float logp = prob[yt] - logf(z2);
        atomicAdd(&d_out[0], -logp * (1.0f / 2048.0f));
        atomicAdd(&d_out[1], (am == yt) ? (1.0f / 2048.0f) : 0.0f);
    }
}

// ---------------------------------------------------------------------------
extern "C" void kernel_launch(void* const* d_in, const int* in_sizes, int n_in,
                              void* d_out, int out_size, void* d_ws, size_t ws_size,
                              hipStream_t stream) {
    const float* gold_table = (const float*)d_in[0];   // (11,256)
    const float* map_table  = (const float*)d_in[1];   // (128,256)
    const float* conv_w     = (const float*)d_in[2];   // (256,256,3,3)
    const float* a_table    = (const float*)d_in[3];   // (4,32)
    const float* a_W        = (const float*)d_in[4];   // (9,32)
    const float* a_b        = (const float*)d_in[5];   // (9,)
    const int*   gs         = (const int*)d_in[6];     // (2048,4,16)
    const int*   actions    = (const int*)d_in[7];     // (2048,3)
    const int*   lms        = (const int*)d_in[8];     // (2048,4,4,8)
    const int*   y          = (const int*)d_in[9];     // (2048,2)
    float* out = (float*)d_out;

    char* ws = (char*)d_ws;
    int*    cnt  = (int*)(ws + 0);                     // 48 B
    int*    list = (int*)(ws + 256);                   // 98,304 B
    ushort* Wa   = (ushort*)(ws + 131072);             // 4,718,592 B
    ushort* c0   = (ushort*)(ws + 4849664);            // 16,777,216 B each
    ushort* c1   = (ushort*)(ws + 21626880);
    ushort* c2   = (ushort*)(ws + 38404096);
    ushort* c3   = (ushort*)(ws + 55181312);           // end 71,958,528
    (void)in_sizes; (void)n_in; (void)out_size; (void)ws_size;

    k_front<<<2048, 256, 0, stream>>>(conv_w, a_table, a_W, a_b, actions,
                                      map_table, lms, cnt, list, Wa, c0, out);
    k_conv <<<2048, 512, 0, stream>>>(c0, Wa, cnt, list, 0, c1);
    k_conv <<<2048, 512, 0, stream>>>(c1, Wa, cnt, list, 1, c2);
    k_conv <<<2048, 512, 0, stream>>>(c2, Wa, cnt, list, 2, c3);
    k_final<<<2048, 256, 0, stream>>>(c0, c1, c2, c3, gold_table, gs, y, out);
}

// Round 11
// 426.437 us; speedup vs baseline: 1.0687x; 1.0687x over previous
//
#include <hip/hip_runtime.h>
#include <hip/hip_bf16.h>

typedef __attribute__((ext_vector_type(4))) float f32x4;
typedef __attribute__((ext_vector_type(8))) short short8;

__device__ __forceinline__ float bf2f(ushort u) {
    union { unsigned int u; float f; } x; x.u = ((unsigned int)u) << 16; return x.f;
}
__device__ __forceinline__ ushort f2bf(float f) {
    union { float f; unsigned int u; } x; x.f = f;
    unsigned int u = x.u;
    unsigned int r = (u + 0x7fffu + ((u >> 16) & 1u)) >> 16;  // RNE
    return (ushort)r;
}
__device__ __forceinline__ void gload16(const ushort* g, ushort* l) {
    __builtin_amdgcn_global_load_lds(
        (const __attribute__((address_space(1))) unsigned int*)g,
        (__attribute__((address_space(3))) unsigned int*)l, 16, 0, 0);
}

// ---------------------------------------------------------------------------
// k_front: grid 2048.  EVERY block b: l_emb for sample b -> c0 (bf16).
// Blocks 0..255 additionally repack Wa[a][o][t*256+i] = bf16(m[a][t]*W[o,i,t]).
// Block 256 additionally zeroes cnt/loss/acc and buckets samples by action.
// ---------------------------------------------------------------------------
__global__ __launch_bounds__(256) void k_front(
    const float* __restrict__ conv_w, const float* __restrict__ a_table,
    const float* __restrict__ a_W, const float* __restrict__ a_b,
    const int* __restrict__ actions, const float* __restrict__ mapt,
    const int* __restrict__ lms, int* __restrict__ cnt,
    int* __restrict__ list, ushort* __restrict__ Wa,
    ushort* __restrict__ c0, float* __restrict__ out_head)
{
    const int bid = blockIdx.x, tid = threadIdx.x;

    // ---- l_emb for sample bid (all blocks) ----
    {
        const int e4 = (tid & 63) * 4, pw = tid >> 6;
        #pragma unroll
        for (int pp = 0; pp < 4; ++pp) {
            const int p = pw * 4 + pp;
            const int* lm = lms + (bid * 16 + p) * 8;
            float4 s = make_float4(0.f, 0.f, 0.f, 0.f);
            #pragma unroll
            for (int k = 0; k < 8; ++k) {
                const int idx = lm[k];
                if (idx) {
                    const float4 v = *(const float4*)&mapt[idx * 256 + e4];
                    s.x += v.x; s.y += v.y; s.z += v.z; s.w += v.w;
                }
            }
            ushort o4[4] = { f2bf(s.x), f2bf(s.y), f2bf(s.z), f2bf(s.w) };
            *(uint2*)&c0[(size_t)(bid * 16 + p) * 256 + e4] = *(const uint2*)o4;
        }
    }

    if (bid < 256) {
        __shared__ float ao[4][9];
        __shared__ float m[4][9];
        if (tid < 36) {
            const int a = tid / 9, t = tid % 9;
            float s = a_b[t];
            for (int c = 0; c < 32; c++) s += a_table[a * 32 + c] * a_W[t * 32 + c];
            ao[a][t] = s;
        }
        __syncthreads();
        if (tid < 4) {
            float mx = -1e30f;
            for (int t = 0; t < 9; t++) mx = fmaxf(mx, ao[tid][t]);
            float e[9], z = 0.f;
            for (int t = 0; t < 9; t++) { e[t] = expf(ao[tid][t] - mx); z += e[t]; }
            for (int t = 0; t < 9; t++) m[tid][t] = e[t] / z;
        }
        __syncthreads();
        const int o = bid;
        float w9[9];
        #pragma unroll
        for (int t = 0; t < 9; t++) w9[t] = conv_w[(o * 256 + tid) * 9 + t];
        #pragma unroll
        for (int a = 0; a < 4; a++)
            #pragma unroll
            for (int t = 0; t < 9; t++)
                Wa[(size_t)((a << 8) + o) * 2304 + t * 256 + tid] = f2bf(m[a][t] * w9[t]);
    } else if (bid == 256) {
        if (tid < 12) cnt[tid] = 0;
        if (tid == 0) { out_head[0] = 0.f; out_head[1] = 0.f; }
        __syncthreads();
        for (int it = 0; it < 24; it++) {
            const int idx = it * 256 + tid;          // 0..6143
            const int jj = idx >> 11, b = idx & 2047;
            const int av = actions[b * 3 + jj];
            const int pos = atomicAdd(&cnt[jj * 4 + av], 1);
            list[((jj * 4 + av) << 11) + pos] = b;
        }
    }
}

// ---------------------------------------------------------------------------
// k_conv v7: R10 structure + K-ROTATION.  Each block starts its K-sweep at
// ks0 = bid % 36 and wraps (accumulation is order-independent), so co-running
// blocks read DIFFERENT 16 KB windows of Wa at any instant -> no L2/L3 line
// hot-spotting (the suspected 90-100 us invariant across R4/R5/R9/R10).
// Everything else identical to R10: BM=128 (om), BN=128 (8 samples), BK=64,
// 512 thr (8 waves 2M x 4N), 3-buffer A via global_load_lds + counted
// vmcnt(2), B staged once in 64 KB XOR-swizzled LDS, 1 block/CU.
// ---------------------------------------------------------------------------
__global__ __launch_bounds__(512, 1) void k_conv(
    const ushort* __restrict__ cur, const ushort* __restrict__ Wa,
    const int* __restrict__ cnt, const int* __restrict__ list,
    const int j, ushort* __restrict__ outp)
{
    __shared__ __align__(16) ushort Alds[3][128 * 64];   // 3 x 16 KB
    __shared__ __align__(16) ushort Blds[8 * 16 * 256];  // 64 KB
    const int tid = threadIdx.x, bid = blockIdx.x;
    const int a = bid & 3, om = (bid >> 2) & 1, grp = bid >> 3;
    const int ca = cnt[j * 4 + a];
    if (grp * 8 >= ca) return;            // uniform exit before any barrier
    const int* la = list + ((j * 4 + a) << 11) + grp * 8;

    const int wid = tid >> 6, lane = tid & 63;
    const int l15 = lane & 15, l4 = lane >> 4;
    const int wm = wid >> 2, wn = wid & 3;

    // ---- stage B once: wave wid -> sample slot wid; XOR-swizzled chunks ----
    {
        const int sw = (grp * 8 + wid < ca) ? la[wid] : la[0];
        const ushort* src = cur + (size_t)sw * 4096;
        const int p = lane >> 2, cg = lane & 3;
        ushort* dst = Blds + wid * 4096 + p * 256;
        const ushort* s2 = src + p * 256;
        #pragma unroll
        for (int qq = 0; qq < 8; ++qq) {
            const int c = qq * 4 + cg;
            const uint4 v = *(const uint4*)(s2 + c * 8);
            *(uint4*)(dst + ((c ^ (p & 7)) * 8)) = v;
        }
    }

    int sid[2]; bool vst[2];
    #pragma unroll
    for (int nf = 0; nf < 2; ++nf) {
        const int sl = wn * 2 + nf;
        vst[nf] = (grp * 8 + sl) < ca;
        sid[nf] = vst[nf] ? la[sl] : 0;
    }

    // ---- A staging: 2 x gload16/thread per stage fills 128x64 (16 KB) ----
    // unit u = qq*512+tid: row=u>>3, c=u&7; src chunk = c ^ (row&7).
    const ushort* wbase = Wa + (size_t)((a << 8) + om * 128) * 2304;
    #define STAGE(buf, k0)                                                     \
        _Pragma("unroll")                                                      \
        for (int qq = 0; qq < 2; ++qq) {                                       \
            const int u = qq * 512 + tid;                                      \
            const int row = u >> 3;                                            \
            const int cc = (u & 7) ^ (row & 7);                                \
            gload16(wbase + (size_t)row * 2304 + (k0) + cc * 8,                \
                    &Alds[buf][u * 8]);                                        \
        }

    f32x4 acc[4][2];
    #pragma unroll
    for (int mf = 0; mf < 4; ++mf) {
        acc[mf][0] = (f32x4){0.f, 0.f, 0.f, 0.f};
        acc[mf][1] = (f32x4){0.f, 0.f, 0.f, 0.f};
    }

    const int ph = l15 >> 2, pw = l15 & 3;
    const short8 bzero = {0, 0, 0, 0, 0, 0, 0, 0};
    const ushort* bbase0 = Blds + (wn * 2 + 0) * 4096;
    const ushort* bbase1 = Blds + (wn * 2 + 1) * 4096;
    const int asw = l15 & 7;             // A-row swizzle key (rr&7 == l15&7)

    // compute body for K-step ks (runtime) reading A buffer rd
    #define COMPUTE(ks, rd)                                                    \
        {                                                                      \
            const int t = (ks) >> 2;                                           \
            const int td = (t * 11) >> 5, tm = t - td * 3;                     \
            const int hh = ph + td - 1, ww = pw + tm - 1;                      \
            const bool xv = (hh >= 0) & (hh < 4) & (ww >= 0) & (ww < 4);       \
            const int brow = xv ? ((hh << 2) + ww) : 0;                        \
            const int rb = brow * 256, rx = brow & 7;                          \
            _Pragma("unroll")                                                  \
            for (int kf = 0; kf < 2; ++kf) {                                   \
                const int bch = ((((ks) & 3) * 8 + kf * 4 + l4) ^ rx) * 8;     \
                short8 b0 = *(const short8*)(bbase0 + rb + bch);               \
                short8 b1 = *(const short8*)(bbase1 + rb + bch);               \
                if (!xv) { b0 = bzero; b1 = bzero; }                           \
                const int acx = ((kf * 4 + l4) ^ asw) * 8;                     \
                _Pragma("unroll")                                              \
                for (int mf = 0; mf < 4; ++mf) {                               \
                    const int rr = wm * 64 + mf * 16 + l15;                    \
                    const short8 af =                                          \
                        *(const short8*)&Alds[rd][rr * 64 + acx];              \
                    acc[mf][0] = __builtin_amdgcn_mfma_f32_16x16x32_bf16(      \
                        af, b0, acc[mf][0], 0, 0, 0);                          \
                    acc[mf][1] = __builtin_amdgcn_mfma_f32_16x16x32_bf16(      \
                        af, b1, acc[mf][1], 0, 0, 0);                          \
                }                                                              \
            }                                                                  \
        }

    // ---- K-rotation: block-specific start offset, wraps mod 36 ----
    const int ks0 = bid % 36;
    STAGE(0, ks0 * 64);
    int k1 = ks0 + 1; if (k1 >= 36) k1 -= 36;
    STAGE(1, k1 * 64);
    asm volatile("s_waitcnt lgkmcnt(0)" ::: "memory");   // B ds_writes done

    int rd = 0, st = 2;                  // buffer indices rotate mod 3
    int kc = ks0;                        // compute window for this iter
    int kp = k1 + 1; if (kp >= 36) kp -= 36;   // prefetch window (+2 ahead)
    for (int i = 0; i < 34; ++i) {
        asm volatile("s_waitcnt vmcnt(2)" ::: "memory"); // stage i landed
        __builtin_amdgcn_s_barrier();                    // visible to all
        __builtin_amdgcn_sched_barrier(0);
        STAGE(st, kp * 64);                              // stays in flight
        COMPUTE(kc, rd);
        kc = (kc == 35) ? 0 : kc + 1;
        kp = (kp == 35) ? 0 : kp + 1;
        rd = (rd == 2) ? 0 : rd + 1;
        st = (st == 2) ? 0 : st + 1;
    }
    asm volatile("s_waitcnt vmcnt(2)" ::: "memory");
    __builtin_amdgcn_s_barrier();
    __builtin_amdgcn_sched_barrier(0);
    COMPUTE(kc, rd);
    kc = (kc == 35) ? 0 : kc + 1;
    rd = (rd == 2) ? 0 : rd + 1;
    asm volatile("s_waitcnt vmcnt(0)" ::: "memory");
    __builtin_amdgcn_s_barrier();
    __builtin_amdgcn_sched_barrier(0);
    COMPUTE(kc, rd);

    // epilogue: C frag col=l15 (=p), row=l4*4+r (=o within 16-tile)
    #pragma unroll
    for (int nf = 0; nf < 2; ++nf) {
        if (!vst[nf]) continue;                      // wave-uniform branch
        const size_t rowb = ((size_t)sid[nf] * 16 + l15) * 256;
        #pragma unroll
        for (int mf = 0; mf < 4; ++mf) {
            const int ob = om * 128 + wm * 64 + mf * 16 + l4 * 4;
            ushort o4[4];
            #pragma unroll
            for (int r = 0; r < 4; r++) o4[r] = f2bf(acc[mf][nf][r]);
            *(uint2*)&outp[rowb + ob] = *(const uint2*)o4;
        }
    }
    #undef STAGE
    #undef COMPUTE
}

// ---------------------------------------------------------------------------
// k_final: grid B=2048.  emb in-block (17-padded LDS), vectorized bf16 dot,
// shfl_xor 16-lane reduction, softmax chain, loss/acc atomics.
// ---------------------------------------------------------------------------
__global__ __launch_bounds__(256) void k_final(
    const ushort* __restrict__ c0, const ushort* __restrict__ c1,
    const ushort* __restrict__ c2, const ushort* __restrict__ c3,
    const float* __restrict__ gold, const int* __restrict__ gs,
    const int* __restrict__ y, float* __restrict__ d_out)
{
    __shared__ float embl[4][272];
    __shared__ float lg[16];
    const int b = blockIdx.x, tid = threadIdx.x;
    {
        const int s = tid >> 6, e0 = (tid & 63) * 4;
        const int* g = gs + b * 64 + s * 16;
        float4 accv = make_float4(0.f, 0.f, 0.f, 0.f);
        #pragma unroll
        for (int l = 0; l < 16; l++) {
            const float4 v = *(const float4*)&gold[g[l] * 256 + e0];
            accv.x += v.x; accv.y += v.y; accv.z += v.z; accv.w += v.w;
        }
        float* dst = &embl[s][(e0 >> 4) * 17 + (e0 & 15)];
        dst[0] = accv.x; dst[1] = accv.y; dst[2] = accv.z; dst[3] = accv.w;
    }
    __syncthreads();
    const int p = tid >> 4, g16 = tid & 15;
    const ushort* rows[4] = {
        c0 + (size_t)(b * 16 + p) * 256, c1 + (size_t)(b * 16 + p) * 256,
        c2 + (size_t)(b * 16 + p) * 256, c3 + (size_t)(b * 16 + p) * 256 };
    float acc = 0.f;
    #pragma unroll
    for (int s = 0; s < 4; s++) {
        const ushort* row = rows[s] + g16 * 16;
        const uint4 v0 = *(const uint4*)row;
        const uint4 v1 = *(const uint4*)(row + 8);
        const ushort* pv0 = (const ushort*)&v0;
        const ushort* pv1 = (const ushort*)&v1;
        const float* eb = &embl[s][g16 * 17];
        #pragma unroll
        for (int q = 0; q < 8; q++) acc += bf2f(pv0[q]) * eb[q];
        #pragma unroll
        for (int q = 0; q < 8; q++) acc += bf2f(pv1[q]) * eb[8 + q];
    }
    acc += __shfl_xor(acc, 1);
    acc += __shfl_xor(acc, 2);
    acc += __shfl_xor(acc, 4);
    acc += __shfl_xor(acc, 8);
    if (g16 == 0) lg[p] = acc;
    __syncthreads();
    if (tid == 0) {
        float mx = -1e30f;
        for (int q = 0; q < 16; q++) mx = fmaxf(mx, lg[q]);
        float ex[16], z = 0.f;
        for (int q = 0; q < 16; q++) { ex[q] = expf(lg[q] - mx); z += ex[q]; }
        float prob[16];
        for (int q = 0; q < 16; q++) {
            prob[q] = ex[q] / z;
            d_out[2 + b * 16 + q] = prob[q];
        }
        int am = 0; float bv = prob[0];
        for (int q = 1; q < 16; q++) if (prob[q] > bv) { bv = prob[q]; am = q; }
        const int yt = y[b * 2] * 4 + y[b * 2 + 1];
        float z2 = 0.f;
        for (int q = 0; q < 16; q++) z2 += expf(prob[q]);
        const float logp = prob[yt] - logf(z2);
        atomicAdd(&d_out[0], -logp * (1.0f / 2048.0f));
        atomicAdd(&d_out[1], (am == yt) ? (1.0f / 2048.0f) : 0.0f);
    }
}

// ---------------------------------------------------------------------------
extern "C" void kernel_launch(void* const* d_in, const int* in_sizes, int n_in,
                              void* d_out, int out_size, void* d_ws, size_t ws_size,
                              hipStream_t stream) {
    const float* gold_table = (const float*)d_in[0];   // (11,256)
    const float* map_table  = (const float*)d_in[1];   // (128,256)
    const float* conv_w     = (const float*)d_in[2];   // (256,256,3,3)
    const float* a_table    = (const float*)d_in[3];   // (4,32)
    const float* a_W        = (const float*)d_in[4];   // (9,32)
    const float* a_b        = (const float*)d_in[5];   // (9,)
    const int*   gs         = (const int*)d_in[6];     // (2048,4,16)
    const int*   actions    = (const int*)d_in[7];     // (2048,3)
    const int*   lms        = (const int*)d_in[8];     // (2048,4,4,8)
    const int*   y          = (const int*)d_in[9];     // (2048,2)
    float* out = (float*)d_out;

    char* ws = (char*)d_ws;
    int*    cnt  = (int*)(ws + 0);                     // 48 B
    int*    list = (int*)(ws + 256);                   // 98,304 B
    ushort* Wa   = (ushort*)(ws + 131072);             // 4,718,592 B
    ushort* c0   = (ushort*)(ws + 4849664);            // 16,777,216 B each
    ushort* c1   = (ushort*)(ws + 21626880);
    ushort* c2   = (ushort*)(ws + 38404096);
    ushort* c3   = (ushort*)(ws + 55181312);           // end 71,958,528
    (void)in_sizes; (void)n_in; (void)out_size; (void)ws_size;

    k_front<<<2048, 256, 0, stream>>>(conv_w, a_table, a_W, a_b, actions,
                                      map_table, lms, cnt, list, Wa, c0, out);
    k_conv <<<2048, 512, 0, stream>>>(c0, Wa, cnt, list, 0, c1);
    k_conv <<<2048, 512, 0, stream>>>(c1, Wa, cnt, list, 1, c2);
    k_conv <<<2048, 512, 0, stream>>>(c2, Wa, cnt, list, 2, c3);
    k_final<<<2048, 256, 0, stream>>>(c0, c1, c2, c3, gold_table, gs, y, out);
}

// Round 12
// 402.542 us; speedup vs baseline: 1.1321x; 1.0594x over previous
//
#include <hip/hip_runtime.h>
#include <hip/hip_bf16.h>

typedef __attribute__((ext_vector_type(4))) float f32x4;
typedef __attribute__((ext_vector_type(8))) short short8;

__device__ __forceinline__ float bf2f(ushort u) {
    union { unsigned int u; float f; } x; x.u = ((unsigned int)u) << 16; return x.f;
}
__device__ __forceinline__ ushort f2bf(float f) {
    union { float f; unsigned int u; } x; x.f = f;
    unsigned int u = x.u;
    unsigned int r = (u + 0x7fffu + ((u >> 16) & 1u)) >> 16;  // RNE
    return (ushort)r;
}
__device__ __forceinline__ void gload16(const ushort* g, ushort* l) {
    __builtin_amdgcn_global_load_lds(
        (const __attribute__((address_space(1))) unsigned int*)g,
        (__attribute__((address_space(3))) unsigned int*)l, 16, 0, 0);
}

// ---------------------------------------------------------------------------
// k_front: grid 2048.  EVERY block b: l_emb for sample b -> c0 (bf16).
// Blocks 0..255 additionally repack Wa[a][o][t*256+i] = bf16(m[a][t]*W[o,i,t]).
// Block 256 additionally zeroes cnt/loss/acc and buckets samples by action.
// ---------------------------------------------------------------------------
__global__ __launch_bounds__(256) void k_front(
    const float* __restrict__ conv_w, const float* __restrict__ a_table,
    const float* __restrict__ a_W, const float* __restrict__ a_b,
    const int* __restrict__ actions, const float* __restrict__ mapt,
    const int* __restrict__ lms, int* __restrict__ cnt,
    int* __restrict__ list, ushort* __restrict__ Wa,
    ushort* __restrict__ c0, float* __restrict__ out_head)
{
    const int bid = blockIdx.x, tid = threadIdx.x;

    // ---- l_emb for sample bid (all blocks) ----
    {
        const int e4 = (tid & 63) * 4, pw = tid >> 6;
        #pragma unroll
        for (int pp = 0; pp < 4; ++pp) {
            const int p = pw * 4 + pp;
            const int* lm = lms + (bid * 16 + p) * 8;
            float4 s = make_float4(0.f, 0.f, 0.f, 0.f);
            #pragma unroll
            for (int k = 0; k < 8; ++k) {
                const int idx = lm[k];
                if (idx) {
                    const float4 v = *(const float4*)&mapt[idx * 256 + e4];
                    s.x += v.x; s.y += v.y; s.z += v.z; s.w += v.w;
                }
            }
            ushort o4[4] = { f2bf(s.x), f2bf(s.y), f2bf(s.z), f2bf(s.w) };
            *(uint2*)&c0[(size_t)(bid * 16 + p) * 256 + e4] = *(const uint2*)o4;
        }
    }

    if (bid < 256) {
        __shared__ float ao[4][9];
        __shared__ float m[4][9];
        if (tid < 36) {
            const int a = tid / 9, t = tid % 9;
            float s = a_b[t];
            for (int c = 0; c < 32; c++) s += a_table[a * 32 + c] * a_W[t * 32 + c];
            ao[a][t] = s;
        }
        __syncthreads();
        if (tid < 4) {
            float mx = -1e30f;
            for (int t = 0; t < 9; t++) mx = fmaxf(mx, ao[tid][t]);
            float e[9], z = 0.f;
            for (int t = 0; t < 9; t++) { e[t] = expf(ao[tid][t] - mx); z += e[t]; }
            for (int t = 0; t < 9; t++) m[tid][t] = e[t] / z;
        }
        __syncthreads();
        const int o = bid;
        float w9[9];
        #pragma unroll
        for (int t = 0; t < 9; t++) w9[t] = conv_w[(o * 256 + tid) * 9 + t];
        #pragma unroll
        for (int a = 0; a < 4; a++)
            #pragma unroll
            for (int t = 0; t < 9; t++)
                Wa[(size_t)((a << 8) + o) * 2304 + t * 256 + tid] = f2bf(m[a][t] * w9[t]);
    } else if (bid == 256) {
        if (tid < 12) cnt[tid] = 0;
        if (tid == 0) { out_head[0] = 0.f; out_head[1] = 0.f; }
        __syncthreads();
        for (int it = 0; it < 24; it++) {
            const int idx = it * 256 + tid;          // 0..6143
            const int jj = idx >> 11, b = idx & 2047;
            const int av = actions[b * 3 + jj];
            const int pos = atomicAdd(&cnt[jj * 4 + av], 1);
            list[((jj * 4 + av) << 11) + pos] = b;
        }
    }
}

// ---------------------------------------------------------------------------
// k_conv v8: R11 pipeline at 2 blocks/CU + T5 setprio.
// BM=128 (om), BN=64 (4 samples), BK=64, 256 thr (4 waves 2M x 2N, wave tile
// 64x32).  LDS = 3x16 KB A (counted-vmcnt rotating) + 32 KB B = 80 KB ->
// 2 blocks/CU, 16 waves/CU: cross-block slip hides each block's
// barrier+vmcnt drain (m114 mechanism).  K-rotation (ks0 = bid%36)
// decorrelates Wa windows.  s_setprio(1) around the MFMA cluster (T5).
// Grid 2048 = 8 slots (a,om) x 256 groups; slot = bid&7 for XCD affinity.
// ---------------------------------------------------------------------------
__global__ __launch_bounds__(256, 2) void k_conv(
    const ushort* __restrict__ cur, const ushort* __restrict__ Wa,
    const int* __restrict__ cnt, const int* __restrict__ list,
    const int j, ushort* __restrict__ outp)
{
    __shared__ __align__(16) ushort Alds[3][128 * 64];   // 3 x 16 KB
    __shared__ __align__(16) ushort Blds[4 * 16 * 256];  // 32 KB
    const int tid = threadIdx.x, bid = blockIdx.x;
    const int a = bid & 3, om = (bid >> 2) & 1, grp = bid >> 3;
    const int ca = cnt[j * 4 + a];
    if (grp * 4 >= ca) return;            // uniform exit before any barrier
    const int* la = list + ((j * 4 + a) << 11) + grp * 4;

    const int wid = tid >> 6, lane = tid & 63;
    const int l15 = lane & 15, l4 = lane >> 4;
    const int wm = wid >> 1, wn = wid & 1;

    // ---- stage B once: wave wid -> sample slot wid; XOR-swizzled chunks ----
    {
        const int sw = (grp * 4 + wid < ca) ? la[wid] : la[0];
        const ushort* src = cur + (size_t)sw * 4096;
        const int p = lane >> 2, cg = lane & 3;
        ushort* dst = Blds + wid * 4096 + p * 256;
        const ushort* s2 = src + p * 256;
        #pragma unroll
        for (int qq = 0; qq < 8; ++qq) {
            const int c = qq * 4 + cg;
            const uint4 v = *(const uint4*)(s2 + c * 8);
            *(uint4*)(dst + ((c ^ (p & 7)) * 8)) = v;
        }
    }

    int sid[2]; bool vst[2];
    #pragma unroll
    for (int nf = 0; nf < 2; ++nf) {
        const int sl = wn * 2 + nf;
        vst[nf] = (grp * 4 + sl) < ca;
        sid[nf] = vst[nf] ? la[sl] : 0;
    }

    // ---- A staging: 4 x gload16/thread per stage fills 128x64 (16 KB) ----
    // unit u = qq*256+tid: row = qq*32 + tid>>3, c = tid&7; src chunk c^(row&7)
    const ushort* wbase = Wa + (size_t)((a << 8) + om * 128) * 2304;
    const int srow = tid >> 3, sc = tid & 7;
    #define STAGE(buf, k0)                                                     \
        _Pragma("unroll")                                                      \
        for (int qq = 0; qq < 4; ++qq) {                                       \
            const int row = qq * 32 + srow;                                    \
            const int cc = sc ^ (row & 7);                                     \
            gload16(wbase + (size_t)row * 2304 + (k0) + cc * 8,                \
                    &Alds[buf][qq * 2048 + tid * 8]);                          \
        }

    f32x4 acc[4][2];
    #pragma unroll
    for (int mf = 0; mf < 4; ++mf) {
        acc[mf][0] = (f32x4){0.f, 0.f, 0.f, 0.f};
        acc[mf][1] = (f32x4){0.f, 0.f, 0.f, 0.f};
    }

    const int ph = l15 >> 2, pw = l15 & 3;
    const short8 bzero = {0, 0, 0, 0, 0, 0, 0, 0};
    const ushort* bbase0 = Blds + (wn * 2 + 0) * 4096;
    const ushort* bbase1 = Blds + (wn * 2 + 1) * 4096;
    const int asw = l15 & 7;             // A-row swizzle key (rr&7 == l15&7)

    // compute body for K-step ks (runtime) reading A buffer rd; T5 setprio
    #define COMPUTE(ks, rd)                                                    \
        {                                                                      \
            const int t = (ks) >> 2;                                           \
            const int td = (t * 11) >> 5, tm = t - td * 3;                     \
            const int hh = ph + td - 1, ww = pw + tm - 1;                      \
            const bool xv = (hh >= 0) & (hh < 4) & (ww >= 0) & (ww < 4);       \
            const int brow = xv ? ((hh << 2) + ww) : 0;                        \
            const int rb = brow * 256, rx = brow & 7;                          \
            __builtin_amdgcn_s_setprio(1);                                     \
            _Pragma("unroll")                                                  \
            for (int kf = 0; kf < 2; ++kf) {                                   \
                const int bch = ((((ks) & 3) * 8 + kf * 4 + l4) ^ rx) * 8;     \
                short8 b0 = *(const short8*)(bbase0 + rb + bch);               \
                short8 b1 = *(const short8*)(bbase1 + rb + bch);               \
                if (!xv) { b0 = bzero; b1 = bzero; }                           \
                const int acx = ((kf * 4 + l4) ^ asw) * 8;                     \
                _Pragma("unroll")                                              \
                for (int mf = 0; mf < 4; ++mf) {                               \
                    const int rr = wm * 64 + mf * 16 + l15;                    \
                    const short8 af =                                          \
                        *(const short8*)&Alds[rd][rr * 64 + acx];              \
                    acc[mf][0] = __builtin_amdgcn_mfma_f32_16x16x32_bf16(      \
                        af, b0, acc[mf][0], 0, 0, 0);                          \
                    acc[mf][1] = __builtin_amdgcn_mfma_f32_16x16x32_bf16(      \
                        af, b1, acc[mf][1], 0, 0, 0);                          \
                }                                                              \
            }                                                                  \
            __builtin_amdgcn_s_setprio(0);                                     \
        }

    // ---- K-rotation: block-specific start offset, wraps mod 36 ----
    const int ks0 = bid % 36;
    STAGE(0, ks0 * 64);
    int k1 = ks0 + 1; if (k1 >= 36) k1 -= 36;
    STAGE(1, k1 * 64);
    asm volatile("s_waitcnt lgkmcnt(0)" ::: "memory");   // B ds_writes done

    int rd = 0, st = 2;                  // buffer indices rotate mod 3
    int kc = ks0;                        // compute window for this iter
    int kp = k1 + 1; if (kp >= 36) kp -= 36;   // prefetch window (+2 ahead)
    for (int i = 0; i < 34; ++i) {
        asm volatile("s_waitcnt vmcnt(4)" ::: "memory"); // stage i landed
        __builtin_amdgcn_s_barrier();                    // visible to all
        __builtin_amdgcn_sched_barrier(0);
        STAGE(st, kp * 64);                              // stays in flight
        COMPUTE(kc, rd);
        kc = (kc == 35) ? 0 : kc + 1;
        kp = (kp == 35) ? 0 : kp + 1;
        rd = (rd == 2) ? 0 : rd + 1;
        st = (st == 2) ? 0 : st + 1;
    }
    asm volatile("s_waitcnt vmcnt(4)" ::: "memory");
    __builtin_amdgcn_s_barrier();
    __builtin_amdgcn_sched_barrier(0);
    COMPUTE(kc, rd);
    kc = (kc == 35) ? 0 : kc + 1;
    rd = (rd == 2) ? 0 : rd + 1;
    asm volatile("s_waitcnt vmcnt(0)" ::: "memory");
    __builtin_amdgcn_s_barrier();
    __builtin_amdgcn_sched_barrier(0);
    COMPUTE(kc, rd);

    // epilogue: C frag col=l15 (=p), row=l4*4+r (=o within 16-tile)
    #pragma unroll
    for (int nf = 0; nf < 2; ++nf) {
        if (!vst[nf]) continue;                      // wave-uniform branch
        const size_t rowb = ((size_t)sid[nf] * 16 + l15) * 256;
        #pragma unroll
        for (int mf = 0; mf < 4; ++mf) {
            const int ob = om * 128 + wm * 64 + mf * 16 + l4 * 4;
            ushort o4[4];
            #pragma unroll
            for (int r = 0; r < 4; r++) o4[r] = f2bf(acc[mf][nf][r]);
            *(uint2*)&outp[rowb + ob] = *(const uint2*)o4;
        }
    }
    #undef STAGE
    #undef COMPUTE
}

// ---------------------------------------------------------------------------
// k_final: grid B=2048.  emb in-block (17-padded LDS), vectorized bf16 dot,
// shfl_xor 16-lane reduction, softmax chain, loss/acc atomics.
// ---------------------------------------------------------------------------
__global__ __launch_bounds__(256) void k_final(
    const ushort* __restrict__ c0, const ushort* __restrict__ c1,
    const ushort* __restrict__ c2, const ushort* __restrict__ c3,
    const float* __restrict__ gold, const int* __restrict__ gs,
    const int* __restrict__ y, float* __restrict__ d_out)
{
    __shared__ float embl[4][272];
    __shared__ float lg[16];
    const int b = blockIdx.x, tid = threadIdx.x;
    {
        const int s = tid >> 6, e0 = (tid & 63) * 4;
        const int* g = gs + b * 64 + s * 16;
        float4 accv = make_float4(0.f, 0.f, 0.f, 0.f);
        #pragma unroll
        for (int l = 0; l < 16; l++) {
            const float4 v = *(const float4*)&gold[g[l] * 256 + e0];
            accv.x += v.x; accv.y += v.y; accv.z += v.z; accv.w += v.w;
        }
        float* dst = &embl[s][(e0 >> 4) * 17 + (e0 & 15)];
        dst[0] = accv.x; dst[1] = accv.y; dst[2] = accv.z; dst[3] = accv.w;
    }
    __syncthreads();
    const int p = tid >> 4, g16 = tid & 15;
    const ushort* rows[4] = {
        c0 + (size_t)(b * 16 + p) * 256, c1 + (size_t)(b * 16 + p) * 256,
        c2 + (size_t)(b * 16 + p) * 256, c3 + (size_t)(b * 16 + p) * 256 };
    float acc = 0.f;
    #pragma unroll
    for (int s = 0; s < 4; s++) {
        const ushort* row = rows[s] + g16 * 16;
        const uint4 v0 = *(const uint4*)row;
        const uint4 v1 = *(const uint4*)(row + 8);
        const ushort* pv0 = (const ushort*)&v0;
        const ushort* pv1 = (const ushort*)&v1;
        const float* eb = &embl[s][g16 * 17];
        #pragma unroll
        for (int q = 0; q < 8; q++) acc += bf2f(pv0[q]) * eb[q];
        #pragma unroll
        for (int q = 0; q < 8; q++) acc += bf2f(pv1[q]) * eb[8 + q];
    }
    acc += __shfl_xor(acc, 1);
    acc += __shfl_xor(acc, 2);
    acc += __shfl_xor(acc, 4);
    acc += __shfl_xor(acc, 8);
    if (g16 == 0) lg[p] = acc;
    __syncthreads();
    if (tid == 0) {
        float mx = -1e30f;
        for (int q = 0; q < 16; q++) mx = fmaxf(mx, lg[q]);
        float ex[16], z = 0.f;
        for (int q = 0; q < 16; q++) { ex[q] = expf(lg[q] - mx); z += ex[q]; }
        float prob[16];
        for (int q = 0; q < 16; q++) {
            prob[q] = ex[q] / z;
            d_out[2 + b * 16 + q] = prob[q];
        }
        int am = 0; float bv = prob[0];
        for (int q = 1; q < 16; q++) if (prob[q] > bv) { bv = prob[q]; am = q; }
        const int yt = y[b * 2] * 4 + y[b * 2 + 1];
        float z2 = 0.f;
        for (int q = 0; q < 16; q++) z2 += expf(prob[q]);
        const float logp = prob[yt] - logf(z2);
        atomicAdd(&d_out[0], -logp * (1.0f / 2048.0f));
        atomicAdd(&d_out[1], (am == yt) ? (1.0f / 2048.0f) : 0.0f);
    }
}

// ---------------------------------------------------------------------------
extern "C" void kernel_launch(void* const* d_in, const int* in_sizes, int n_in,
                              void* d_out, int out_size, void* d_ws, size_t ws_size,
                              hipStream_t stream) {
    const float* gold_table = (const float*)d_in[0];   // (11,256)
    const float* map_table  = (const float*)d_in[1];   // (128,256)
    const float* conv_w     = (const float*)d_in[2];   // (256,256,3,3)
    const float* a_table    = (const float*)d_in[3];   // (4,32)
    const float* a_W        = (const float*)d_in[4];   // (9,32)
    const float* a_b        = (const float*)d_in[5];   // (9,)
    const int*   gs         = (const int*)d_in[6];     // (2048,4,16)
    const int*   actions    = (const int*)d_in[7];     // (2048,3)
    const int*   lms        = (const int*)d_in[8];     // (2048,4,4,8)
    const int*   y          = (const int*)d_in[9];     // (2048,2)
    float* out = (float*)d_out;

    char* ws = (char*)d_ws;
    int*    cnt  = (int*)(ws + 0);                     // 48 B
    int*    list = (int*)(ws + 256);                   // 98,304 B
    ushort* Wa   = (ushort*)(ws + 131072);             // 4,718,592 B
    ushort* c0   = (ushort*)(ws + 4849664);            // 16,777,216 B each
    ushort* c1   = (ushort*)(ws + 21626880);
    ushort* c2   = (ushort*)(ws + 38404096);
    ushort* c3   = (ushort*)(ws + 55181312);           // end 71,958,528
    (void)in_sizes; (void)n_in; (void)out_size; (void)ws_size;

    k_front<<<2048, 256, 0, stream>>>(conv_w, a_table, a_W, a_b, actions,
                                      map_table, lms, cnt, list, Wa, c0, out);
    k_conv <<<2048, 256, 0, stream>>>(c0, Wa, cnt, list, 0, c1);
    k_conv <<<2048, 256, 0, stream>>>(c1, Wa, cnt, list, 1, c2);
    k_conv <<<2048, 256, 0, stream>>>(c2, Wa, cnt, list, 2, c3);
    k_final<<<2048, 256, 0, stream>>>(c0, c1, c2, c3, gold_table, gs, y, out);
}